// Round 1
// baseline (10474.774 us; speedup 1.0000x reference)
//
#include <hip/hip_runtime.h>
#include <hip/hip_bf16.h>
#include <math.h>

// Swin Transformer 3D block, MI355X.
// B=8, D=8, H=56, W=56, C=96. Window (2,7,7) -> N=98 tokens, 2048 windows.
// NH=3 heads, HD=32. MLP hidden 384.
//
// Kernel A: per-window fused LN1 + QKV + attention(+rel-pos-bias) + proj + residual.
// Kernel B: per-64-token-tile fused LN2 + MLP(GELU exact) + residual, in-place on d_out.

#define NTOK 98
#define CH   96
#define NHD  3
#define HD   32
#define BLKA 512
#define BLKB 256
#define TB   64   // tokens per block in kernel B

__device__ __forceinline__ int row_of(int wid, int t) {
    // wid: 0..2047 -> (b, d0, h0, w0); t: 0..97 -> (td, th, tw)
    int b = wid >> 8, rem = wid & 255;
    int d0 = rem >> 6, h0 = (rem >> 3) & 7, w0 = rem & 7;
    int td = t / 49, tr = t % 49, th = tr / 7, tw = tr % 7;
    int dd = d0 * 2 + td, hh = h0 * 7 + th, ww = w0 * 7 + tw;
    return ((b * 8 + dd) * 56 + hh) * 56 + ww;   // token row; *96 for channel base
}

__global__ __launch_bounds__(BLKA) void attn_kernel(
    const float* __restrict__ x,
    const float* __restrict__ n1w, const float* __restrict__ n1b,
    const float* __restrict__ qkv_w, const float* __restrict__ qkv_b,
    const float* __restrict__ proj_w, const float* __restrict__ proj_b,
    const float* __restrict__ rpb,
    float* __restrict__ out)
{
    __shared__ __hip_bfloat16 xs[NTOK][CH];      // LN'd window input   18816 B
    __shared__ __hip_bfloat16 ob[NTOK][CH];      // attn out (all heads)18816 B
    __shared__ float qh[NTOK][33];               // 12936 B
    __shared__ float kh[NTOK][33];
    __shared__ float vh[NTOK][33];
    __shared__ float sc[NTOK][99];               // 38808 B    total ~115 KB

    const int wid = blockIdx.x;
    const int tid = threadIdx.x;
    const int lane = tid & 63;
    const int wv = tid >> 6;                     // 8 waves

    // ---- stage + LayerNorm1 (one wave per token) ----
    for (int t = wv; t < NTOK; t += 8) {
        int base = row_of(wid, t) * CH;
        float v0 = x[base + lane];
        float v1 = (lane < 32) ? x[base + 64 + lane] : 0.f;
        float s = v0 + v1;
        for (int m = 32; m; m >>= 1) s += __shfl_xor(s, m, 64);
        float mean = s * (1.f / 96.f);
        float e0 = v0 - mean;
        float e1 = (lane < 32) ? (v1 - mean) : 0.f;
        float ss = e0 * e0 + e1 * e1;
        for (int m = 32; m; m >>= 1) ss += __shfl_xor(ss, m, 64);
        float rstd = rsqrtf(ss * (1.f / 96.f) + 1e-5f);
        xs[t][lane] = __float2bfloat16(e0 * rstd * n1w[lane] + n1b[lane]);
        if (lane < 32)
            xs[t][64 + lane] = __float2bfloat16(e1 * rstd * n1w[64 + lane] + n1b[64 + lane]);
    }
    __syncthreads();

    const float scale = 0.17677669529663687f;    // 32^-0.5

    for (int h = 0; h < NHD; ++h) {
        // ---- QKV for this head: 3*98*32 outputs ----
        for (int j = tid; j < 3 * NTOK * HD; j += BLKA) {
            int which = j / (NTOK * HD);
            int r = j % (NTOK * HD);
            int t = r >> 5, d = r & 31;
            int o = which * 96 + h * 32 + d;
            float acc = qkv_b[o];
            const float* wrow = qkv_w + o * 96;
            #pragma unroll 8
            for (int i = 0; i < 96; ++i)
                acc += __bfloat162float(xs[t][i]) * wrow[i];
            if (which == 0)      qh[t][d] = acc * scale;
            else if (which == 1) kh[t][d] = acc;
            else                 vh[t][d] = acc;
        }
        __syncthreads();

        // ---- scores = q.k^T + rel_pos_bias ----
        for (int j = tid; j < NTOK * NTOK; j += BLKA) {
            int t = j / NTOK, u = j % NTOK;
            int td = t / 49, tr = t % 49, th = tr / 7, tw = tr % 7;
            int ud = u / 49, ur = u % 49, uh = ur / 7, uw = ur % 7;
            int ridx = (td - ud + 1) * 169 + (th - uh + 6) * 13 + (tw - uw + 6);
            float acc = rpb[ridx * 3 + h];
            #pragma unroll
            for (int d = 0; d < 32; ++d) acc += qh[t][d] * kh[u][d];
            sc[t][u] = acc;
        }
        __syncthreads();

        // ---- softmax over rows (4 lanes per row) ----
        {
            int g = tid >> 2, l = tid & 3;
            if (g < NTOK) {
                float mx = -1e30f;
                for (int u = l; u < NTOK; u += 4) mx = fmaxf(mx, sc[g][u]);
                mx = fmaxf(mx, __shfl_xor(mx, 1, 4));
                mx = fmaxf(mx, __shfl_xor(mx, 2, 4));
                float sum = 0.f;
                for (int u = l; u < NTOK; u += 4) {
                    float e = __expf(sc[g][u] - mx);
                    sc[g][u] = e;
                    sum += e;
                }
                sum += __shfl_xor(sum, 1, 4);
                sum += __shfl_xor(sum, 2, 4);
                float inv = 1.f / sum;
                for (int u = l; u < NTOK; u += 4) sc[g][u] *= inv;
            }
        }
        __syncthreads();

        // ---- PV ----
        for (int j = tid; j < NTOK * HD; j += BLKA) {
            int t = j >> 5, d = j & 31;
            float acc = 0.f;
            for (int u = 0; u < NTOK; ++u) acc += sc[t][u] * vh[u][d];
            ob[t][h * 32 + d] = __float2bfloat16(acc);
        }
        __syncthreads();   // protects qh/kh/vh/sc for next head
    }

    // ---- proj + shortcut residual ----
    for (int j = tid; j < NTOK * CH; j += BLKA) {
        int t = j / 96, o = j % 96;
        float acc = proj_b[o];
        const float* wrow = proj_w + o * 96;
        #pragma unroll 8
        for (int i = 0; i < 96; ++i)
            acc += __bfloat162float(ob[t][i]) * wrow[i];
        int idx = row_of(wid, t) * 96 + o;
        out[idx] = x[idx] + acc;
    }
}

__global__ __launch_bounds__(BLKB) void mlp_kernel(
    const float* __restrict__ n2w, const float* __restrict__ n2b,
    const float* __restrict__ w1, const float* __restrict__ b1,
    const float* __restrict__ w2, const float* __restrict__ b2,
    float* __restrict__ io)
{
    __shared__ float xn[TB][97];
    __shared__ float hb[TB][97];
    const int tid = threadIdx.x;
    const int base = blockIdx.x * (TB * 96);

    // ---- load tile (coalesced) ----
    #pragma unroll
    for (int k = 0; k < 24; ++k) {
        int j = tid + k * BLKB;
        xn[j / 96][j % 96] = io[base + j];
    }
    __syncthreads();

    // ---- LayerNorm2 in place (4 lanes per token) ----
    {
        int t = tid >> 2, l = tid & 3;
        float s = 0.f, ss = 0.f;
        for (int c = l; c < 96; c += 4) { float v = xn[t][c]; s += v; ss += v * v; }
        s += __shfl_xor(s, 1, 4);  s += __shfl_xor(s, 2, 4);
        ss += __shfl_xor(ss, 1, 4); ss += __shfl_xor(ss, 2, 4);
        float m = s * (1.f / 96.f);
        float var = ss * (1.f / 96.f) - m * m;
        float rstd = rsqrtf(var + 1e-5f);
        for (int c = l; c < 96; c += 4)
            xn[t][c] = (xn[t][c] - m) * rstd * n2w[c] + n2b[c];
    }

    float yacc[24];
    #pragma unroll
    for (int k = 0; k < 24; ++k) yacc[k] = 0.f;

    // ---- MLP in 4 chunks of 96 hidden units ----
    for (int c4 = 0; c4 < 4; ++c4) {
        __syncthreads();   // LN done (first iter) / hb reads done (later iters)
        #pragma unroll
        for (int k = 0; k < 24; ++k) {
            int j = tid + k * BLKB;
            int t = j / 96, o = j % 96;
            int oo = c4 * 96 + o;
            float acc = b1[oo];
            const float* wrow = w1 + oo * 96;
            #pragma unroll 8
            for (int i = 0; i < 96; ++i) acc += xn[t][i] * wrow[i];
            hb[t][o] = acc * 0.5f * (1.f + erff(acc * 0.70710678118654752f));
        }
        __syncthreads();
        #pragma unroll
        for (int k = 0; k < 24; ++k) {
            int j = tid + k * BLKB;
            int t = j / 96, o = j % 96;
            float acc = 0.f;
            const float* wrow = w2 + o * 384 + c4 * 96;
            #pragma unroll 8
            for (int i = 0; i < 96; ++i) acc += hb[t][i] * wrow[i];
            yacc[k] += acc;
        }
    }

    // ---- residual + bias, in-place write ----
    #pragma unroll
    for (int k = 0; k < 24; ++k) {
        int j = tid + k * BLKB;
        int o = j % 96;
        io[base + j] = io[base + j] + yacc[k] + b2[o];
    }
}

extern "C" void kernel_launch(void* const* d_in, const int* in_sizes, int n_in,
                              void* d_out, int out_size, void* d_ws, size_t ws_size,
                              hipStream_t stream) {
    const float* x      = (const float*)d_in[0];
    const float* n1w    = (const float*)d_in[1];
    const float* n1b    = (const float*)d_in[2];
    const float* qkv_w  = (const float*)d_in[3];
    const float* qkv_b  = (const float*)d_in[4];
    const float* proj_w = (const float*)d_in[5];
    const float* proj_b = (const float*)d_in[6];
    const float* rpb    = (const float*)d_in[7];
    const float* n2w    = (const float*)d_in[8];
    const float* n2b    = (const float*)d_in[9];
    const float* fc1_w  = (const float*)d_in[10];
    const float* fc1_b  = (const float*)d_in[11];
    const float* fc2_w  = (const float*)d_in[12];
    const float* fc2_b  = (const float*)d_in[13];
    float* out = (float*)d_out;

    attn_kernel<<<2048, BLKA, 0, stream>>>(x, n1w, n1b, qkv_w, qkv_b,
                                           proj_w, proj_b, rpb, out);
    mlp_kernel<<<3136, BLKB, 0, stream>>>(n2w, n2b, fc1_w, fc1_b, fc2_w, fc2_b, out);
}

// Round 2
// 1286.669 us; speedup vs baseline: 8.1410x; 8.1410x over previous
//
#include <hip/hip_runtime.h>
#include <hip/hip_bf16.h>
#include <math.h>

// Swin Transformer 3D block, MI355X (gfx950).
// Kernel A (attn): per-window LN1 + QKV + attention + proj + residual.
//   Weight matmuls use wave-uniform weight rows (SGPR broadcast via s_load),
//   lanes = tokens, LDS activations conflict-free. Scores/PV 2x2 reg tiles.
// Kernel B (mlp): 128-token tiles, bf16 MFMA (16x16x32) for fc1/fc2,
//   weights staged bf16 in LDS per 64-hidden chunk, GELU in-register.

#define NTOK 98

typedef __attribute__((ext_vector_type(8))) short bf16x8;
typedef __attribute__((ext_vector_type(4))) float f32x4;

__device__ __forceinline__ int row_of(int wid, int t) {
    int b = wid >> 8, rem = wid & 255;
    int d0 = rem >> 6, h0 = (rem >> 3) & 7, w0 = rem & 7;
    int td = t / 49, tr = t % 49, th = tr / 7, tw = tr % 7;
    int dd = d0 * 2 + td, hh = h0 * 7 + th, ww = w0 * 7 + tw;
    return ((b * 8 + dd) * 56 + hh) * 56 + ww;
}

__device__ __forceinline__ float bf2f(unsigned short u) {
    union { unsigned int i; float f; } c; c.i = ((unsigned int)u) << 16; return c.f;
}
__device__ __forceinline__ unsigned short f2bf(float f) {
    __hip_bfloat16 h = __float2bfloat16(f);
    unsigned short u; __builtin_memcpy(&u, &h, 2); return u;
}
__device__ __forceinline__ void decomp(int t, int& a, int& b, int& c) {
    a = t / 49; int r = t - 49 * a; b = r / 7; c = r - 7 * b;
}

// ---------------------------------------------------------------- attention
__global__ __launch_bounds__(512) void attn_kernel(
    const float* __restrict__ x,
    const float* __restrict__ n1w, const float* __restrict__ n1b,
    const float* __restrict__ qkv_w, const float* __restrict__ qkv_b,
    const float* __restrict__ proj_w, const float* __restrict__ proj_b,
    const float* __restrict__ rpb,
    float* __restrict__ out)
{
    __shared__ float bufA[10848];          // xs[98][100] fp32, later yT[96][113]
    __shared__ float qT[32][113];
    __shared__ float kT[32][113];
    __shared__ float vT[32][113];
    __shared__ float sc[98][99];
    __shared__ __hip_bfloat16 obr[98][104];  // attn out, row-major bf16

    const int wid = blockIdx.x, tid = threadIdx.x;
    const int lane = tid & 63, wv = tid >> 6;

    // ---- LN1 -> xs row-major [98][100] (one wave per token)
    for (int t = wv; t < NTOK; t += 8) {
        int base = row_of(wid, t) * 96;
        float v0 = x[base + lane];
        float v1 = (lane < 32) ? x[base + 64 + lane] : 0.f;
        float s = v0 + v1;
        #pragma unroll
        for (int m = 32; m; m >>= 1) s += __shfl_xor(s, m, 64);
        float mean = s * (1.f / 96.f);
        float e0 = v0 - mean;
        float e1 = (lane < 32) ? (v1 - mean) : 0.f;
        float ss = e0 * e0 + e1 * e1;
        #pragma unroll
        for (int m = 32; m; m >>= 1) ss += __shfl_xor(ss, m, 64);
        float rstd = rsqrtf(ss * (1.f / 96.f) + 1e-5f);
        bufA[t * 100 + lane] = e0 * rstd * n1w[lane] + n1b[lane];
        if (lane < 32)
            bufA[t * 100 + 64 + lane] = e1 * rstd * n1w[64 + lane] + n1b[64 + lane];
    }
    __syncthreads();

    const float scale = 0.17677669529663687f;

    for (int h = 0; h < 3; ++h) {
        // ---- QKV: wave-uniform weight rows, lanes = tokens
        #pragma unroll
        for (int q3 = 0; q3 < 3; ++q3) {
            int ob = __builtin_amdgcn_readfirstlane(wv * 12 + q3 * 4);
            int r0 = ((ob + 0) >> 5) * 96 + h * 32 + ((ob + 0) & 31);
            int r1 = ((ob + 1) >> 5) * 96 + h * 32 + ((ob + 1) & 31);
            int r2 = ((ob + 2) >> 5) * 96 + h * 32 + ((ob + 2) & 31);
            int r3 = ((ob + 3) >> 5) * 96 + h * 32 + ((ob + 3) & 31);
            const float* w0 = qkv_w + r0 * 96;
            const float* w1 = qkv_w + r1 * 96;
            const float* w2 = qkv_w + r2 * 96;
            const float* w3 = qkv_w + r3 * 96;
            for (int p = 0; p < 2; ++p) {
                int t = p * 64 + lane;
                if (t < NTOK) {
                    const float* xr = &bufA[t * 100];
                    float a0 = 0, a1 = 0, a2 = 0, a3 = 0;
                    #pragma unroll
                    for (int i4 = 0; i4 < 24; ++i4) {
                        f32x4 xv = *(const f32x4*)&xr[i4 * 4];
                        #pragma unroll
                        for (int e = 0; e < 4; ++e) {
                            float xe = xv[e];
                            int i = i4 * 4 + e;
                            a0 += xe * w0[i]; a1 += xe * w1[i];
                            a2 += xe * w2[i]; a3 += xe * w3[i];
                        }
                    }
                    a0 += qkv_b[r0]; a1 += qkv_b[r1]; a2 += qkv_b[r2]; a3 += qkv_b[r3];
                    #pragma unroll
                    for (int j = 0; j < 4; ++j) {
                        int o = ob + j;
                        float v = (j == 0) ? a0 : (j == 1) ? a1 : (j == 2) ? a2 : a3;
                        int d = o & 31, wh = o >> 5;
                        if (wh == 0)      qT[d][t] = v * scale;
                        else if (wh == 1) kT[d][t] = v;
                        else              vT[d][t] = v;
                    }
                }
            }
        }
        __syncthreads();

        // ---- scores = q.k^T + bias, 2x2 register tiles
        for (int j = tid; j < 49 * 49; j += 512) {
            int tp = j / 49, up = j - tp * 49;
            int t0 = tp * 2, u0 = up * 2;
            float s00 = 0, s01 = 0, s10 = 0, s11 = 0;
            #pragma unroll 8
            for (int d = 0; d < 32; ++d) {
                float q0 = qT[d][t0], q1 = qT[d][t0 + 1];
                float k0 = kT[d][u0], k1 = kT[d][u0 + 1];
                s00 += q0 * k0; s01 += q0 * k1;
                s10 += q1 * k0; s11 += q1 * k1;
            }
            int ta, tb, tc, Ta, Tb, Tc, ua, ub, uc, Ua, Ub, Uc;
            decomp(t0, ta, tb, tc); decomp(t0 + 1, Ta, Tb, Tc);
            decomp(u0, ua, ub, uc); decomp(u0 + 1, Ua, Ub, Uc);
            int i00 = (ta - ua + 1) * 169 + (tb - ub + 6) * 13 + (tc - uc + 6);
            int i01 = (ta - Ua + 1) * 169 + (tb - Ub + 6) * 13 + (tc - Uc + 6);
            int i10 = (Ta - ua + 1) * 169 + (Tb - ub + 6) * 13 + (Tc - uc + 6);
            int i11 = (Ta - Ua + 1) * 169 + (Tb - Ub + 6) * 13 + (Tc - Uc + 6);
            sc[t0][u0]         = s00 + rpb[i00 * 3 + h];
            sc[t0][u0 + 1]     = s01 + rpb[i01 * 3 + h];
            sc[t0 + 1][u0]     = s10 + rpb[i10 * 3 + h];
            sc[t0 + 1][u0 + 1] = s11 + rpb[i11 * 3 + h];
        }
        __syncthreads();

        // ---- softmax (4 lanes per row)
        {
            int g = tid >> 2, l = tid & 3;
            if (g < NTOK) {
                float mx = -1e30f;
                for (int u = l; u < NTOK; u += 4) mx = fmaxf(mx, sc[g][u]);
                mx = fmaxf(mx, __shfl_xor(mx, 1, 4));
                mx = fmaxf(mx, __shfl_xor(mx, 2, 4));
                float sum = 0.f;
                for (int u = l; u < NTOK; u += 4) {
                    float e = __expf(sc[g][u] - mx);
                    sc[g][u] = e;
                    sum += e;
                }
                sum += __shfl_xor(sum, 1, 4);
                sum += __shfl_xor(sum, 2, 4);
                float inv = 1.f / sum;
                for (int u = l; u < NTOK; u += 4) sc[g][u] *= inv;
            }
        }
        __syncthreads();

        // ---- PV, 2t x 2d register tiles
        for (int j = tid; j < 49 * 16; j += 512) {
            int tp = j >> 4, dp = j & 15;
            int t0 = tp * 2, d0 = dp * 2;
            float o00 = 0, o01 = 0, o10 = 0, o11 = 0;
            for (int u = 0; u < NTOK; ++u) {
                float s0 = sc[t0][u], s1 = sc[t0 + 1][u];
                float v0 = vT[d0][u], v1 = vT[d0 + 1][u];
                o00 += s0 * v0; o01 += s0 * v1;
                o10 += s1 * v0; o11 += s1 * v1;
            }
            unsigned int p0 = (unsigned int)f2bf(o00) | ((unsigned int)f2bf(o01) << 16);
            unsigned int p1 = (unsigned int)f2bf(o10) | ((unsigned int)f2bf(o11) << 16);
            *(unsigned int*)&obr[t0][h * 32 + d0]     = p0;
            *(unsigned int*)&obr[t0 + 1][h * 32 + d0] = p1;
        }
        __syncthreads();
    }

    // ---- proj: wave-uniform weight rows; write yT into bufA (xs is dead)
    #pragma unroll
    for (int q3 = 0; q3 < 3; ++q3) {
        int ob = __builtin_amdgcn_readfirstlane(wv * 12 + q3 * 4);
        const float* w0 = proj_w + (ob + 0) * 96;
        const float* w1 = proj_w + (ob + 1) * 96;
        const float* w2 = proj_w + (ob + 2) * 96;
        const float* w3 = proj_w + (ob + 3) * 96;
        float pb0 = proj_b[ob + 0], pb1 = proj_b[ob + 1];
        float pb2 = proj_b[ob + 2], pb3 = proj_b[ob + 3];
        for (int p = 0; p < 2; ++p) {
            int t = p * 64 + lane;
            if (t < NTOK) {
                const __hip_bfloat16* orow = &obr[t][0];
                float a0 = 0, a1 = 0, a2 = 0, a3 = 0;
                #pragma unroll
                for (int i8 = 0; i8 < 12; ++i8) {
                    bf16x8 ov = *(const bf16x8*)&orow[i8 * 8];
                    #pragma unroll
                    for (int e = 0; e < 8; ++e) {
                        float xe = bf2f((unsigned short)ov[e]);
                        int i = i8 * 8 + e;
                        a0 += xe * w0[i]; a1 += xe * w1[i];
                        a2 += xe * w2[i]; a3 += xe * w3[i];
                    }
                }
                bufA[(ob + 0) * 113 + t] = a0 + pb0;
                bufA[(ob + 1) * 113 + t] = a1 + pb1;
                bufA[(ob + 2) * 113 + t] = a2 + pb2;
                bufA[(ob + 3) * 113 + t] = a3 + pb3;
            }
        }
    }
    __syncthreads();

    // ---- residual + coalesced store
    for (int j = tid; j < NTOK * 96; j += 512) {
        int t = j / 96, c = j - t * 96;
        int idx = row_of(wid, t) * 96 + c;
        out[idx] = x[idx] + bufA[c * 113 + t];
    }
}

// ---------------------------------------------------------------- MLP (MFMA)
__global__ __launch_bounds__(256) void mlp_kernel(
    const float* __restrict__ n2w, const float* __restrict__ n2b,
    const float* __restrict__ w1, const float* __restrict__ b1,
    const float* __restrict__ w2, const float* __restrict__ b2,
    float* __restrict__ io)
{
    __shared__ __hip_bfloat16 XS[128][104];   // LN'd tokens, k=0..95
    __shared__ __hip_bfloat16 HS[128][72];    // GELU(H) chunk, k=0..63
    __shared__ __hip_bfloat16 W1S[64][104];   // w1 chunk rows (hidden), k=0..95
    __shared__ __hip_bfloat16 W2S[96][72];    // w2 rows (out ch), k=chunk 64

    const int tid = threadIdx.x, lane = tid & 63, wv = tid >> 6;
    const int tok0 = blockIdx.x * 128;

    // ---- LN2 -> XS bf16 (one wave per token)
    for (int t = wv; t < 128; t += 4) {
        int base = (tok0 + t) * 96;
        float v0 = io[base + lane];
        float v1 = (lane < 32) ? io[base + 64 + lane] : 0.f;
        float s = v0 + v1;
        #pragma unroll
        for (int m = 32; m; m >>= 1) s += __shfl_xor(s, m, 64);
        float mean = s * (1.f / 96.f);
        float e0 = v0 - mean;
        float e1 = (lane < 32) ? (v1 - mean) : 0.f;
        float ss = e0 * e0 + e1 * e1;
        #pragma unroll
        for (int m = 32; m; m >>= 1) ss += __shfl_xor(ss, m, 64);
        float rstd = rsqrtf(ss * (1.f / 96.f) + 1e-5f);
        XS[t][lane] = __float2bfloat16(e0 * rstd * n2w[lane] + n2b[lane]);
        if (lane < 32)
            XS[t][64 + lane] = __float2bfloat16(e1 * rstd * n2w[64 + lane] + n2b[64 + lane]);
    }

    f32x4 yacc[2][6];
    #pragma unroll
    for (int mt = 0; mt < 2; ++mt)
        #pragma unroll
        for (int nt = 0; nt < 6; ++nt)
            yacc[mt][nt] = (f32x4){0.f, 0.f, 0.f, 0.f};

    const int arow = lane & 15;            // A row / B col within tile
    const int kgrp = (lane >> 4) * 8;      // k offset of this lane's 8 elems
    const int drow = (lane >> 4) * 4;      // C/D row group
    const int m0 = wv * 32;                // this wave's 32 tokens

    for (int hc = 0; hc < 6; ++hc) {
        __syncthreads();   // previous chunk's reads (and LN writes) complete
        #pragma unroll
        for (int k = 0; k < 24; ++k) {
            int idx = tid + k * 256;                   // 6144 = 64*96
            int r = idx / 96, c = idx - r * 96;
            W1S[r][c] = __float2bfloat16(w1[hc * 6144 + idx]);
        }
        #pragma unroll
        for (int k = 0; k < 24; ++k) {
            int idx = tid + k * 256;                   // 6144 = 96*64
            int r = idx >> 6, c = idx & 63;
            W2S[r][c] = __float2bfloat16(w2[r * 384 + hc * 64 + c]);
        }
        __syncthreads();

        // GEMM1: H(32x64) = XS(32x96) @ W1S^T
        f32x4 hacc[2][4];
        #pragma unroll
        for (int mt = 0; mt < 2; ++mt)
            #pragma unroll
            for (int nt = 0; nt < 4; ++nt)
                hacc[mt][nt] = (f32x4){0.f, 0.f, 0.f, 0.f};
        #pragma unroll
        for (int k = 0; k < 3; ++k) {
            bf16x8 a0 = *(const bf16x8*)&XS[m0 + arow][k * 32 + kgrp];
            bf16x8 a1 = *(const bf16x8*)&XS[m0 + 16 + arow][k * 32 + kgrp];
            #pragma unroll
            for (int nt = 0; nt < 4; ++nt) {
                bf16x8 b = *(const bf16x8*)&W1S[nt * 16 + arow][k * 32 + kgrp];
                hacc[0][nt] = __builtin_amdgcn_mfma_f32_16x16x32_bf16(a0, b, hacc[0][nt], 0, 0, 0);
                hacc[1][nt] = __builtin_amdgcn_mfma_f32_16x16x32_bf16(a1, b, hacc[1][nt], 0, 0, 0);
            }
        }
        // bias + GELU -> HS (C/D layout: row = drow+r, col = arow)
        #pragma unroll
        for (int mt = 0; mt < 2; ++mt)
            #pragma unroll
            for (int nt = 0; nt < 4; ++nt)
                #pragma unroll
                for (int r = 0; r < 4; ++r) {
                    float v = hacc[mt][nt][r] + b1[hc * 64 + nt * 16 + arow];
                    float g = 0.5f * v * (1.f + erff(v * 0.70710678118654752f));
                    HS[m0 + mt * 16 + drow + r][nt * 16 + arow] = __float2bfloat16(g);
                }
        // GEMM2 partial: Y(32x96) += HS(32x64) @ W2S^T   (same-wave HS, compiler waits)
        #pragma unroll
        for (int k = 0; k < 2; ++k) {
            bf16x8 a0 = *(const bf16x8*)&HS[m0 + arow][k * 32 + kgrp];
            bf16x8 a1 = *(const bf16x8*)&HS[m0 + 16 + arow][k * 32 + kgrp];
            #pragma unroll
            for (int nt = 0; nt < 6; ++nt) {
                bf16x8 b = *(const bf16x8*)&W2S[nt * 16 + arow][k * 32 + kgrp];
                yacc[0][nt] = __builtin_amdgcn_mfma_f32_16x16x32_bf16(a0, b, yacc[0][nt], 0, 0, 0);
                yacc[1][nt] = __builtin_amdgcn_mfma_f32_16x16x32_bf16(a1, b, yacc[1][nt], 0, 0, 0);
            }
        }
    }

    // ---- epilogue: residual + fc2 bias, in-place
    #pragma unroll
    for (int mt = 0; mt < 2; ++mt)
        #pragma unroll
        for (int nt = 0; nt < 6; ++nt)
            #pragma unroll
            for (int r = 0; r < 4; ++r) {
                int t = tok0 + m0 + mt * 16 + drow + r;
                int c = nt * 16 + arow;
                int idx = t * 96 + c;
                io[idx] = io[idx] + yacc[mt][nt][r] + b2[c];
            }
}

extern "C" void kernel_launch(void* const* d_in, const int* in_sizes, int n_in,
                              void* d_out, int out_size, void* d_ws, size_t ws_size,
                              hipStream_t stream) {
    const float* x      = (const float*)d_in[0];
    const float* n1w    = (const float*)d_in[1];
    const float* n1b    = (const float*)d_in[2];
    const float* qkv_w  = (const float*)d_in[3];
    const float* qkv_b  = (const float*)d_in[4];
    const float* proj_w = (const float*)d_in[5];
    const float* proj_b = (const float*)d_in[6];
    const float* rpb    = (const float*)d_in[7];
    const float* n2w    = (const float*)d_in[8];
    const float* n2b    = (const float*)d_in[9];
    const float* fc1_w  = (const float*)d_in[10];
    const float* fc1_b  = (const float*)d_in[11];
    const float* fc2_w  = (const float*)d_in[12];
    const float* fc2_b  = (const float*)d_in[13];
    float* out = (float*)d_out;

    attn_kernel<<<2048, 512, 0, stream>>>(x, n1w, n1b, qkv_w, qkv_b,
                                          proj_w, proj_b, rpb, out);
    mlp_kernel<<<1568, 256, 0, stream>>>(n2w, n2b, fc1_w, fc1_b, fc2_w, fc2_b, out);
}

// Round 3
// 530.114 us; speedup vs baseline: 19.7595x; 2.4272x over previous
//
#include <hip/hip_runtime.h>
#include <hip/hip_bf16.h>
#include <math.h>

// Swin Transformer 3D block, MI355X (gfx950).
// attn_kernel: per-window, fully MFMA (16x16x32 bf16): LN1 -> QKV GEMM ->
//   scores (+rel-pos bias, reg-softmax) -> PV -> proj GEMM -> residual.
//   Tokens padded 98->112 (7 M-tiles of 16). Pad rows carry garbage that is
//   provably confined (per-row independence of MFMA); k-pad cols are zeroed.
// mlp_kernel: unchanged from R2 (128-token tiles, MFMA fc1/fc2, fused GELU).

#define NTOK 98

typedef __attribute__((ext_vector_type(8))) short bf16x8;
typedef __attribute__((ext_vector_type(4))) float f32x4;

__device__ __forceinline__ int row_of(int wid, int t) {
    int b = wid >> 8, rem = wid & 255;
    int d0 = rem >> 6, h0 = (rem >> 3) & 7, w0 = rem & 7;
    int td = t / 49, tr = t % 49, th = tr / 7, tw = tr % 7;
    int dd = d0 * 2 + td, hh = h0 * 7 + th, ww = w0 * 7 + tw;
    return ((b * 8 + dd) * 56 + hh) * 56 + ww;
}

__device__ __forceinline__ int pcode(int t) {   // rel-pos code of a token
    int a = t / 49, r = t - 49 * a, b = r / 7, c = r - 7 * b;
    return a * 169 + b * 13 + c;
}

// ---------------------------------------------------------------- attention
__global__ __launch_bounds__(512) void attn_kernel(
    const float* __restrict__ x,
    const float* __restrict__ n1w, const float* __restrict__ n1b,
    const float* __restrict__ qkv_w, const float* __restrict__ qkv_b,
    const float* __restrict__ proj_w, const float* __restrict__ proj_b,
    const float* __restrict__ rpb,
    float* __restrict__ out)
{
    __shared__ __align__(16) __hip_bfloat16 XS[112][104];  // LN'd x; later attn-out (OB)
    __shared__ __align__(16) __hip_bfloat16 Qb[112][104];
    __shared__ __align__(16) __hip_bfloat16 Kb[112][104];
    __shared__ __align__(16) __hip_bfloat16 vT[96][136];   // V^T per head-dim rows
    __shared__ __align__(16) __hip_bfloat16 Pb[112][136];  // softmax probs; also WBUF
    __shared__ int rowbase[112];

    __hip_bfloat16 (*WBUF)[104] = (__hip_bfloat16 (*)[104])&Pb[0][0];

    const int wid = blockIdx.x, tid = threadIdx.x;
    const int lane = tid & 63, wv = tid >> 6;
    const int l15 = lane & 15;            // A/B fragment row; C/D col
    const int koff = (lane >> 4) * 8;     // fragment k offset
    const int drow = (lane >> 4) * 4;     // C/D row group

    // ---- rowbase table + vT k-tail zero (disjoint regions, pre-barrier)
    for (int t = tid; t < NTOK; t += 512) rowbase[t] = row_of(wid, t) * 96;
    for (int i = tid; i < 96 * 30; i += 512) {
        int r = i / 30, c = 98 + (i - r * 30);
        vT[r][c] = __float2bfloat16(0.f);
    }

    // ---- LN1 -> XS bf16 (one wave per token)
    {
        float w0 = n1w[lane], b0 = n1b[lane];
        float w1 = (lane < 32) ? n1w[64 + lane] : 0.f;
        float b1 = (lane < 32) ? n1b[64 + lane] : 0.f;
        for (int t = wv; t < NTOK; t += 8) {
            int base = row_of(wid, t) * 96;
            float v0 = x[base + lane];
            float v1 = (lane < 32) ? x[base + 64 + lane] : 0.f;
            float s = v0 + v1;
            #pragma unroll
            for (int m = 32; m; m >>= 1) s += __shfl_xor(s, m, 64);
            float mean = s * (1.f / 96.f);
            float e0 = v0 - mean;
            float e1 = (lane < 32) ? (v1 - mean) : 0.f;
            float ss = e0 * e0 + e1 * e1;
            #pragma unroll
            for (int m = 32; m; m >>= 1) ss += __shfl_xor(ss, m, 64);
            float rstd = rsqrtf(ss * (1.f / 96.f) + 1e-5f);
            XS[t][lane] = __float2bfloat16(e0 * rstd * w0 + b0);
            if (lane < 32)
                XS[t][64 + lane] = __float2bfloat16(e1 * rstd * w1 + b1);
        }
    }

    // ---- QKV GEMM, 3 chunks (q, k, v); W chunk staged bf16 in WBUF
    for (int c = 0; c < 3; ++c) {
        __syncthreads();                       // WBUF free / LN done (c==0)
        const float* wsrc = qkv_w + c * 9216;
        for (int i = tid; i < 9216; i += 512)
            WBUF[i / 96][i % 96] = __float2bfloat16(wsrc[i]);
        __syncthreads();
        for (int tile = wv; tile < 42; tile += 8) {
            int m0 = (tile / 6) * 16, n0 = (tile % 6) * 16;
            f32x4 acc = {0.f, 0.f, 0.f, 0.f};
            #pragma unroll
            for (int ks = 0; ks < 3; ++ks) {
                bf16x8 a = *(const bf16x8*)&XS[m0 + l15][ks * 32 + koff];
                bf16x8 b = *(const bf16x8*)&WBUF[n0 + l15][ks * 32 + koff];
                acc = __builtin_amdgcn_mfma_f32_16x16x32_bf16(a, b, acc, 0, 0, 0);
            }
            float bb = qkv_b[c * 96 + n0 + l15];
            if (c == 0) {
                #pragma unroll
                for (int r = 0; r < 4; ++r)
                    Qb[m0 + drow + r][n0 + l15] =
                        __float2bfloat16((acc[r] + bb) * 0.17677669529663687f);
            } else if (c == 1) {
                #pragma unroll
                for (int r = 0; r < 4; ++r)
                    Kb[m0 + drow + r][n0 + l15] = __float2bfloat16(acc[r] + bb);
            } else {
                #pragma unroll
                for (int r = 0; r < 4; ++r) {
                    int u = m0 + drow + r;
                    if (u < NTOK) vT[n0 + l15][u] = __float2bfloat16(acc[r] + bb);
                }
            }
        }
    }
    __syncthreads();                           // Q/K/vT ready; WBUF reads done

    // ---- zero P k-tail cols [98,128) (Pb overlaps WBUF -> must be after barrier)
    for (int i = tid; i < 112 * 30; i += 512) {
        int r = i / 30, c = 98 + (i - r * 30);
        Pb[r][c] = __float2bfloat16(0.f);
    }

    // ---- per-lane rel-pos code tables (score waves only)
    int pt_[4], pu_[7];
    if (wv < 7) {
        int m0 = wv * 16;
        #pragma unroll
        for (int r = 0; r < 4; ++r) {
            int t = m0 + drow + r; if (t > 97) t = 97;
            pt_[r] = pcode(t);
        }
        #pragma unroll
        for (int T = 0; T < 7; ++T) {
            int u = T * 16 + l15; if (u > 97) u = 97;
            pu_[T] = pcode(u);
        }
    }

    // ---- heads: scores (MFMA) + reg softmax -> P; PV (MFMA) -> OB(=XS)
    for (int h = 0; h < 3; ++h) {
        if (wv < 7) {
            int m0 = wv * 16;
            bf16x8 aq = *(const bf16x8*)&Qb[m0 + l15][h * 32 + koff];
            f32x4 s[7];
            #pragma unroll
            for (int T = 0; T < 7; ++T) {
                bf16x8 bk = *(const bf16x8*)&Kb[T * 16 + l15][h * 32 + koff];
                f32x4 z = {0.f, 0.f, 0.f, 0.f};
                s[T] = __builtin_amdgcn_mfma_f32_16x16x32_bf16(aq, bk, z, 0, 0, 0);
            }
            #pragma unroll
            for (int T = 0; T < 7; ++T)
                #pragma unroll
                for (int r = 0; r < 4; ++r)
                    s[T][r] += rpb[(pt_[r] - pu_[T] + 253) * 3 + h];
            if (l15 >= 2) {                    // mask u = 98..111 (tile 6)
                s[6][0] = -1e30f; s[6][1] = -1e30f;
                s[6][2] = -1e30f; s[6][3] = -1e30f;
            }
            #pragma unroll
            for (int r = 0; r < 4; ++r) {
                float mx = s[0][r];
                #pragma unroll
                for (int T = 1; T < 7; ++T) mx = fmaxf(mx, s[T][r]);
                mx = fmaxf(mx, __shfl_xor(mx, 1));
                mx = fmaxf(mx, __shfl_xor(mx, 2));
                mx = fmaxf(mx, __shfl_xor(mx, 4));
                mx = fmaxf(mx, __shfl_xor(mx, 8));
                float p[7], sum = 0.f;
                #pragma unroll
                for (int T = 0; T < 7; ++T) { p[T] = __expf(s[T][r] - mx); sum += p[T]; }
                sum += __shfl_xor(sum, 1);
                sum += __shfl_xor(sum, 2);
                sum += __shfl_xor(sum, 4);
                sum += __shfl_xor(sum, 8);
                float inv = 1.f / sum;
                #pragma unroll
                for (int T = 0; T < 7; ++T)
                    Pb[m0 + drow + r][T * 16 + l15] = __float2bfloat16(p[T] * inv);
            }
        }
        __syncthreads();                       // P ready (and tail zeros visible)

        for (int task = wv; task < 14; task += 8) {
            int m0 = (task >> 1) * 16, n0 = (task & 1) * 16;
            f32x4 acc = {0.f, 0.f, 0.f, 0.f};
            #pragma unroll
            for (int ks = 0; ks < 4; ++ks) {
                bf16x8 a = *(const bf16x8*)&Pb[m0 + l15][ks * 32 + koff];
                bf16x8 b = *(const bf16x8*)&vT[h * 32 + n0 + l15][ks * 32 + koff];
                acc = __builtin_amdgcn_mfma_f32_16x16x32_bf16(a, b, acc, 0, 0, 0);
            }
            #pragma unroll
            for (int r = 0; r < 4; ++r)
                XS[m0 + drow + r][h * 32 + n0 + l15] = __float2bfloat16(acc[r]);
        }
        __syncthreads();                       // PV done before next head's P write
    }

    // ---- proj GEMM: OB(=XS) @ proj_w^T + residual
    for (int i = tid; i < 9216; i += 512)      // overwrites Pb: P is dead
        WBUF[i / 96][i % 96] = __float2bfloat16(proj_w[i]);
    __syncthreads();
    for (int tile = wv; tile < 42; tile += 8) {
        int m0 = (tile / 6) * 16, n0 = (tile % 6) * 16;
        f32x4 acc = {0.f, 0.f, 0.f, 0.f};
        #pragma unroll
        for (int ks = 0; ks < 3; ++ks) {
            bf16x8 a = *(const bf16x8*)&XS[m0 + l15][ks * 32 + koff];
            bf16x8 b = *(const bf16x8*)&WBUF[n0 + l15][ks * 32 + koff];
            acc = __builtin_amdgcn_mfma_f32_16x16x32_bf16(a, b, acc, 0, 0, 0);
        }
        float pb = proj_b[n0 + l15];
        #pragma unroll
        for (int r = 0; r < 4; ++r) {
            int t = m0 + drow + r;
            if (t < NTOK) {
                int idx = rowbase[t] + n0 + l15;
                out[idx] = x[idx] + acc[r] + pb;
            }
        }
    }
}

// ---------------------------------------------------------------- MLP (MFMA)
__global__ __launch_bounds__(256) void mlp_kernel(
    const float* __restrict__ n2w, const float* __restrict__ n2b,
    const float* __restrict__ w1, const float* __restrict__ b1,
    const float* __restrict__ w2, const float* __restrict__ b2,
    float* __restrict__ io)
{
    __shared__ __hip_bfloat16 XS[128][104];
    __shared__ __hip_bfloat16 HS[128][72];
    __shared__ __hip_bfloat16 W1S[64][104];
    __shared__ __hip_bfloat16 W2S[96][72];

    const int tid = threadIdx.x, lane = tid & 63, wv = tid >> 6;
    const int tok0 = blockIdx.x * 128;

    for (int t = wv; t < 128; t += 4) {
        int base = (tok0 + t) * 96;
        float v0 = io[base + lane];
        float v1 = (lane < 32) ? io[base + 64 + lane] : 0.f;
        float s = v0 + v1;
        #pragma unroll
        for (int m = 32; m; m >>= 1) s += __shfl_xor(s, m, 64);
        float mean = s * (1.f / 96.f);
        float e0 = v0 - mean;
        float e1 = (lane < 32) ? (v1 - mean) : 0.f;
        float ss = e0 * e0 + e1 * e1;
        #pragma unroll
        for (int m = 32; m; m >>= 1) ss += __shfl_xor(ss, m, 64);
        float rstd = rsqrtf(ss * (1.f / 96.f) + 1e-5f);
        XS[t][lane] = __float2bfloat16(e0 * rstd * n2w[lane] + n2b[lane]);
        if (lane < 32)
            XS[t][64 + lane] = __float2bfloat16(e1 * rstd * n2w[64 + lane] + n2b[64 + lane]);
    }

    f32x4 yacc[2][6];
    #pragma unroll
    for (int mt = 0; mt < 2; ++mt)
        #pragma unroll
        for (int nt = 0; nt < 6; ++nt)
            yacc[mt][nt] = (f32x4){0.f, 0.f, 0.f, 0.f};

    const int arow = lane & 15;
    const int kgrp = (lane >> 4) * 8;
    const int drow = (lane >> 4) * 4;
    const int m0 = wv * 32;

    for (int hc = 0; hc < 6; ++hc) {
        __syncthreads();
        #pragma unroll
        for (int k = 0; k < 24; ++k) {
            int idx = tid + k * 256;
            int r = idx / 96, c = idx - r * 96;
            W1S[r][c] = __float2bfloat16(w1[hc * 6144 + idx]);
        }
        #pragma unroll
        for (int k = 0; k < 24; ++k) {
            int idx = tid + k * 256;
            int r = idx >> 6, c = idx & 63;
            W2S[r][c] = __float2bfloat16(w2[r * 384 + hc * 64 + c]);
        }
        __syncthreads();

        f32x4 hacc[2][4];
        #pragma unroll
        for (int mt = 0; mt < 2; ++mt)
            #pragma unroll
            for (int nt = 0; nt < 4; ++nt)
                hacc[mt][nt] = (f32x4){0.f, 0.f, 0.f, 0.f};
        #pragma unroll
        for (int k = 0; k < 3; ++k) {
            bf16x8 a0 = *(const bf16x8*)&XS[m0 + arow][k * 32 + kgrp];
            bf16x8 a1 = *(const bf16x8*)&XS[m0 + 16 + arow][k * 32 + kgrp];
            #pragma unroll
            for (int nt = 0; nt < 4; ++nt) {
                bf16x8 b = *(const bf16x8*)&W1S[nt * 16 + arow][k * 32 + kgrp];
                hacc[0][nt] = __builtin_amdgcn_mfma_f32_16x16x32_bf16(a0, b, hacc[0][nt], 0, 0, 0);
                hacc[1][nt] = __builtin_amdgcn_mfma_f32_16x16x32_bf16(a1, b, hacc[1][nt], 0, 0, 0);
            }
        }
        #pragma unroll
        for (int mt = 0; mt < 2; ++mt)
            #pragma unroll
            for (int nt = 0; nt < 4; ++nt)
                #pragma unroll
                for (int r = 0; r < 4; ++r) {
                    float v = hacc[mt][nt][r] + b1[hc * 64 + nt * 16 + arow];
                    float g = 0.5f * v * (1.f + erff(v * 0.70710678118654752f));
                    HS[m0 + mt * 16 + drow + r][nt * 16 + arow] = __float2bfloat16(g);
                }
        #pragma unroll
        for (int k = 0; k < 2; ++k) {
            bf16x8 a0 = *(const bf16x8*)&HS[m0 + arow][k * 32 + kgrp];
            bf16x8 a1 = *(const bf16x8*)&HS[m0 + 16 + arow][k * 32 + kgrp];
            #pragma unroll
            for (int nt = 0; nt < 6; ++nt) {
                bf16x8 b = *(const bf16x8*)&W2S[nt * 16 + arow][k * 32 + kgrp];
                yacc[0][nt] = __builtin_amdgcn_mfma_f32_16x16x32_bf16(a0, b, yacc[0][nt], 0, 0, 0);
                yacc[1][nt] = __builtin_amdgcn_mfma_f32_16x16x32_bf16(a1, b, yacc[1][nt], 0, 0, 0);
            }
        }
    }

    #pragma unroll
    for (int mt = 0; mt < 2; ++mt)
        #pragma unroll
        for (int nt = 0; nt < 6; ++nt)
            #pragma unroll
            for (int r = 0; r < 4; ++r) {
                int t = tok0 + m0 + mt * 16 + drow + r;
                int c = nt * 16 + arow;
                int idx = t * 96 + c;
                io[idx] = io[idx] + yacc[mt][nt][r] + b2[c];
            }
}

extern "C" void kernel_launch(void* const* d_in, const int* in_sizes, int n_in,
                              void* d_out, int out_size, void* d_ws, size_t ws_size,
                              hipStream_t stream) {
    const float* x      = (const float*)d_in[0];
    const float* n1w    = (const float*)d_in[1];
    const float* n1b    = (const float*)d_in[2];
    const float* qkv_w  = (const float*)d_in[3];
    const float* qkv_b  = (const float*)d_in[4];
    const float* proj_w = (const float*)d_in[5];
    const float* proj_b = (const float*)d_in[6];
    const float* rpb    = (const float*)d_in[7];
    const float* n2w    = (const float*)d_in[8];
    const float* n2b    = (const float*)d_in[9];
    const float* fc1_w  = (const float*)d_in[10];
    const float* fc1_b  = (const float*)d_in[11];
    const float* fc2_w  = (const float*)d_in[12];
    const float* fc2_b  = (const float*)d_in[13];
    float* out = (float*)d_out;

    attn_kernel<<<2048, 512, 0, stream>>>(x, n1w, n1b, qkv_w, qkv_b,
                                          proj_w, proj_b, rpb, out);
    mlp_kernel<<<1568, 256, 0, stream>>>(n2w, n2b, fc1_w, fc1_b, fc2_w, fc2_b, out);
}

// Round 4
// 495.014 us; speedup vs baseline: 21.1605x; 1.0709x over previous
//
#include <hip/hip_runtime.h>
#include <hip/hip_bf16.h>
#include <math.h>

// Swin Transformer 3D block, MI355X (gfx950).
// prep_kernel: one-shot (per launch) weight bf16 conversion into d_ws
//   (Q-scale folded) + rel-pos bias expanded into MFMA C-fragment layout.
// attn_kernel: per-window MFMA pipeline; head loop is BARRIER-FREE:
//   each wave owns one 16-row m-strip (scores -> reg softmax -> private
//   P strip in LDS -> PV -> OB), no __syncthreads between heads.
// mlp_kernel: as R3 but stages pre-converted bf16 weights (no VALU converts).
// All kernels fall back to fp32-convert paths if ws_size < WS_NEED.

#define NTOK 98
#define SCALE 0.17677669529663687f

// ws element offsets (bf16 region), then biasM f32 at byte 221184
#define WS_PROJ   27648
#define WS_FC1    36864
#define WS_FC2    73728
#define WS_BF16_N 110592
#define WS_BIASM_BYTE 221184
#define WS_NEED   371712

typedef __attribute__((ext_vector_type(8))) short bf16x8;
typedef __attribute__((ext_vector_type(4))) float f32x4;

__device__ __forceinline__ int row_of(int wid, int t) {
    int b = wid >> 8, rem = wid & 255;
    int d0 = rem >> 6, h0 = (rem >> 3) & 7, w0 = rem & 7;
    int td = t / 49, tr = t % 49, th = tr / 7, tw = tr % 7;
    int dd = d0 * 2 + td, hh = h0 * 7 + th, ww = w0 * 7 + tw;
    return ((b * 8 + dd) * 56 + hh) * 56 + ww;
}

__device__ __forceinline__ int pcode(int t) {
    int a = t / 49, r = t - 49 * a, b = r / 7, c = r - 7 * b;
    return a * 169 + b * 13 + c;
}

// ---------------------------------------------------------------- prep
__global__ __launch_bounds__(256) void prep_kernel(
    const float* __restrict__ qkv_w, const float* __restrict__ proj_w,
    const float* __restrict__ fc1_w, const float* __restrict__ fc2_w,
    const float* __restrict__ rpb,
    __hip_bfloat16* __restrict__ wsb, float* __restrict__ biasM)
{
    int i = blockIdx.x * 256 + threadIdx.x;
    if (i < WS_BF16_N) {
        float v;
        if (i < 27648)      { v = qkv_w[i]; if (i < 9216) v *= SCALE; }
        else if (i < 36864) v = proj_w[i - 27648];
        else if (i < 73728) v = fc1_w[i - 36864];
        else                v = fc2_w[i - 73728];
        wsb[i] = __float2bfloat16(v);
    } else if (i < WS_BF16_N + 37632) {
        int j = i - WS_BF16_N;
        int r = j & 3, lane = (j >> 2) & 63;
        int rest = j >> 8;
        int T = rest % 7; rest /= 7;
        int mt = rest % 7, h = rest / 7;
        int t = mt * 16 + ((lane >> 4) << 2) + r; if (t > 97) t = 97;
        int u = T * 16 + (lane & 15);             if (u > 97) u = 97;
        int ridx = pcode(t) - pcode(u) + 253;
        biasM[j] = rpb[ridx * 3 + h];
    }
}

// ---------------------------------------------------------------- attention
__global__ __launch_bounds__(512) void attn_kernel(
    const float* __restrict__ x,
    const float* __restrict__ n1w, const float* __restrict__ n1b,
    const float* __restrict__ qkv_w, const float* __restrict__ qkv_b,
    const float* __restrict__ proj_w, const float* __restrict__ proj_b,
    const float* __restrict__ rpb,
    const __hip_bfloat16* __restrict__ wsb, const float* __restrict__ biasM,
    int usews,
    float* __restrict__ out)
{
    __shared__ __align__(16) __hip_bfloat16 XS[112][104];  // LN'd x; later OB
    __shared__ __align__(16) __hip_bfloat16 Qb[112][104];
    __shared__ __align__(16) __hip_bfloat16 Kb[112][104];
    __shared__ __align__(16) __hip_bfloat16 vT[96][136];
    __shared__ __align__(16) __hip_bfloat16 Pstr[7][16][136]; // per-wave P strips
    __shared__ int rowbase[112];

    __hip_bfloat16 (*WSTG)[104] = (__hip_bfloat16 (*)[104])&Pstr[0][0][0]; // 19968B < 30464B

    const int wid = blockIdx.x, tid = threadIdx.x;
    const int lane = tid & 63, wv = tid >> 6;
    const int l15 = lane & 15;
    const int koff = (lane >> 4) * 8;
    const int drow = (lane >> 4) * 4;

    for (int t = tid; t < NTOK; t += 512) rowbase[t] = row_of(wid, t) * 96;
    for (int i = tid; i < 96 * 38; i += 512) {       // vT tail cols [98,136)
        int r = i / 38, c = 98 + (i - r * 38);
        vT[r][c] = __float2bfloat16(0.f);
    }

    // ---- LN1 -> XS bf16
    {
        float w0 = n1w[lane], b0 = n1b[lane];
        float w1 = (lane < 32) ? n1w[64 + lane] : 0.f;
        float b1 = (lane < 32) ? n1b[64 + lane] : 0.f;
        for (int t = wv; t < NTOK; t += 8) {
            int base = rowbase[t];
            float v0 = x[base + lane];
            float v1 = (lane < 32) ? x[base + 64 + lane] : 0.f;
            float s = v0 + v1;
            #pragma unroll
            for (int m = 32; m; m >>= 1) s += __shfl_xor(s, m, 64);
            float mean = s * (1.f / 96.f);
            float e0 = v0 - mean;
            float e1 = (lane < 32) ? (v1 - mean) : 0.f;
            float ss = e0 * e0 + e1 * e1;
            #pragma unroll
            for (int m = 32; m; m >>= 1) ss += __shfl_xor(ss, m, 64);
            float rstd = rsqrtf(ss * (1.f / 96.f) + 1e-5f);
            XS[t][lane] = __float2bfloat16(e0 * rstd * w0 + b0);
            if (lane < 32)
                XS[t][64 + lane] = __float2bfloat16(e1 * rstd * w1 + b1);
        }
    }

    // ---- QKV GEMM, 3 chunks; weights staged into WSTG
    for (int c = 0; c < 3; ++c) {
        __syncthreads();
        if (usews) {
            const bf16x8* src = (const bf16x8*)(wsb + c * 9216);
            for (int v = tid; v < 1152; v += 512) {
                int r = v / 12, c8 = (v - r * 12) * 8;
                *(bf16x8*)&WSTG[r][c8] = src[v];
            }
        } else {
            const float* wsrc = qkv_w + c * 9216;
            for (int i = tid; i < 9216; i += 512)
                WSTG[i / 96][i % 96] = __float2bfloat16(wsrc[i]);
        }
        __syncthreads();
        for (int tile = wv; tile < 42; tile += 8) {
            int m0 = (tile / 6) * 16, n0 = (tile % 6) * 16;
            f32x4 acc = {0.f, 0.f, 0.f, 0.f};
            #pragma unroll
            for (int ks = 0; ks < 3; ++ks) {
                bf16x8 a = *(const bf16x8*)&XS[m0 + l15][ks * 32 + koff];
                bf16x8 b = *(const bf16x8*)&WSTG[n0 + l15][ks * 32 + koff];
                acc = __builtin_amdgcn_mfma_f32_16x16x32_bf16(a, b, acc, 0, 0, 0);
            }
            float bb = qkv_b[c * 96 + n0 + l15];
            if (c == 0) {
                float qb_ = usews ? bb * SCALE : bb;
                #pragma unroll
                for (int r = 0; r < 4; ++r) {
                    float q = usews ? (acc[r] + qb_) : ((acc[r] + qb_) * SCALE);
                    Qb[m0 + drow + r][n0 + l15] = __float2bfloat16(q);
                }
            } else if (c == 1) {
                #pragma unroll
                for (int r = 0; r < 4; ++r)
                    Kb[m0 + drow + r][n0 + l15] = __float2bfloat16(acc[r] + bb);
            } else {
                #pragma unroll
                for (int r = 0; r < 4; ++r) {
                    int u = m0 + drow + r;
                    if (u < NTOK) vT[n0 + l15][u] = __float2bfloat16(acc[r] + bb);
                }
            }
        }
    }
    __syncthreads();     // Q/K/vT ready; WSTG reads done (Pstr region free)

    // ---- BARRIER-FREE head loop: wave wv (<7) owns m-strip wv
    if (wv < 7) {
        const int m0 = wv * 16;
        // zero own strip's k-tail cols [112,136)
        for (int i = lane; i < 16 * 24; i += 64) {
            int r = i / 24, c = 112 + (i - r * 24);
            Pstr[wv][r][c] = __float2bfloat16(0.f);
        }
        for (int h = 0; h < 3; ++h) {
            bf16x8 aq = *(const bf16x8*)&Qb[m0 + l15][h * 32 + koff];
            f32x4 s[7];
            #pragma unroll
            for (int T = 0; T < 7; ++T) {
                bf16x8 bk = *(const bf16x8*)&Kb[T * 16 + l15][h * 32 + koff];
                f32x4 z = {0.f, 0.f, 0.f, 0.f};
                s[T] = __builtin_amdgcn_mfma_f32_16x16x32_bf16(aq, bk, z, 0, 0, 0);
            }
            if (usews) {
                const float* bmb = biasM + ((h * 7 + wv) * 7) * 256 + (lane << 2);
                #pragma unroll
                for (int T = 0; T < 7; ++T) {
                    f32x4 bv = *(const f32x4*)(bmb + (T << 8));
                    s[T][0] += bv[0]; s[T][1] += bv[1];
                    s[T][2] += bv[2]; s[T][3] += bv[3];
                }
            } else {
                int pt_[4], pu_[7];
                #pragma unroll
                for (int r = 0; r < 4; ++r) {
                    int t = m0 + drow + r; if (t > 97) t = 97;
                    pt_[r] = pcode(t);
                }
                #pragma unroll
                for (int T = 0; T < 7; ++T) {
                    int u = T * 16 + l15; if (u > 97) u = 97;
                    pu_[T] = pcode(u);
                }
                #pragma unroll
                for (int T = 0; T < 7; ++T)
                    #pragma unroll
                    for (int r = 0; r < 4; ++r)
                        s[T][r] += rpb[(pt_[r] - pu_[T] + 253) * 3 + h];
            }
            if (l15 >= 2) {                    // mask u = 98..111
                s[6][0] = -1e30f; s[6][1] = -1e30f;
                s[6][2] = -1e30f; s[6][3] = -1e30f;
            }
            #pragma unroll
            for (int r = 0; r < 4; ++r) {
                float mx = s[0][r];
                #pragma unroll
                for (int T = 1; T < 7; ++T) mx = fmaxf(mx, s[T][r]);
                mx = fmaxf(mx, __shfl_xor(mx, 1));
                mx = fmaxf(mx, __shfl_xor(mx, 2));
                mx = fmaxf(mx, __shfl_xor(mx, 4));
                mx = fmaxf(mx, __shfl_xor(mx, 8));
                float p[7], sum = 0.f;
                #pragma unroll
                for (int T = 0; T < 7; ++T) { p[T] = __expf(s[T][r] - mx); sum += p[T]; }
                sum += __shfl_xor(sum, 1);
                sum += __shfl_xor(sum, 2);
                sum += __shfl_xor(sum, 4);
                sum += __shfl_xor(sum, 8);
                float inv = 1.f / sum;
                #pragma unroll
                for (int T = 0; T < 7; ++T)
                    Pstr[wv][drow + r][T * 16 + l15] = __float2bfloat16(p[T] * inv);
            }
            // PV for own strip (reads only rows this wave wrote; waitcnt only)
            #pragma unroll
            for (int nt = 0; nt < 2; ++nt) {
                int n0 = nt * 16;
                f32x4 acc = {0.f, 0.f, 0.f, 0.f};
                #pragma unroll
                for (int ks = 0; ks < 4; ++ks) {
                    bf16x8 a = *(const bf16x8*)&Pstr[wv][l15][ks * 32 + koff];
                    bf16x8 b = *(const bf16x8*)&vT[h * 32 + n0 + l15][ks * 32 + koff];
                    acc = __builtin_amdgcn_mfma_f32_16x16x32_bf16(a, b, acc, 0, 0, 0);
                }
                #pragma unroll
                for (int r = 0; r < 4; ++r)
                    XS[m0 + drow + r][h * 32 + n0 + l15] = __float2bfloat16(acc[r]);
            }
        }
    }
    __syncthreads();     // OB complete; Pstr region free for proj weights

    // ---- proj GEMM + residual
    if (usews) {
        const bf16x8* src = (const bf16x8*)(wsb + WS_PROJ);
        for (int v = tid; v < 1152; v += 512) {
            int r = v / 12, c8 = (v - r * 12) * 8;
            *(bf16x8*)&WSTG[r][c8] = src[v];
        }
    } else {
        for (int i = tid; i < 9216; i += 512)
            WSTG[i / 96][i % 96] = __float2bfloat16(proj_w[i]);
    }
    __syncthreads();
    for (int tile = wv; tile < 42; tile += 8) {
        int m0 = (tile / 6) * 16, n0 = (tile % 6) * 16;
        f32x4 acc = {0.f, 0.f, 0.f, 0.f};
        #pragma unroll
        for (int ks = 0; ks < 3; ++ks) {
            bf16x8 a = *(const bf16x8*)&XS[m0 + l15][ks * 32 + koff];
            bf16x8 b = *(const bf16x8*)&WSTG[n0 + l15][ks * 32 + koff];
            acc = __builtin_amdgcn_mfma_f32_16x16x32_bf16(a, b, acc, 0, 0, 0);
        }
        float pb = proj_b[n0 + l15];
        #pragma unroll
        for (int r = 0; r < 4; ++r) {
            int t = m0 + drow + r;
            if (t < NTOK) {
                int idx = rowbase[t] + n0 + l15;
                out[idx] = x[idx] + acc[r] + pb;
            }
        }
    }
}

// ---------------------------------------------------------------- MLP (MFMA)
__global__ __launch_bounds__(256) void mlp_kernel(
    const float* __restrict__ n2w, const float* __restrict__ n2b,
    const float* __restrict__ w1, const float* __restrict__ b1,
    const float* __restrict__ w2, const float* __restrict__ b2,
    const __hip_bfloat16* __restrict__ wsb, int usews,
    float* __restrict__ io)
{
    __shared__ __hip_bfloat16 XS[128][104];
    __shared__ __hip_bfloat16 HS[128][72];
    __shared__ __hip_bfloat16 W1S[64][104];
    __shared__ __hip_bfloat16 W2S[96][72];

    const int tid = threadIdx.x, lane = tid & 63, wv = tid >> 6;
    const int tok0 = blockIdx.x * 128;

    for (int t = wv; t < 128; t += 4) {
        int base = (tok0 + t) * 96;
        float v0 = io[base + lane];
        float v1 = (lane < 32) ? io[base + 64 + lane] : 0.f;
        float s = v0 + v1;
        #pragma unroll
        for (int m = 32; m; m >>= 1) s += __shfl_xor(s, m, 64);
        float mean = s * (1.f / 96.f);
        float e0 = v0 - mean;
        float e1 = (lane < 32) ? (v1 - mean) : 0.f;
        float ss = e0 * e0 + e1 * e1;
        #pragma unroll
        for (int m = 32; m; m >>= 1) ss += __shfl_xor(ss, m, 64);
        float rstd = rsqrtf(ss * (1.f / 96.f) + 1e-5f);
        XS[t][lane] = __float2bfloat16(e0 * rstd * n2w[lane] + n2b[lane]);
        if (lane < 32)
            XS[t][64 + lane] = __float2bfloat16(e1 * rstd * n2w[64 + lane] + n2b[64 + lane]);
    }

    f32x4 yacc[2][6];
    #pragma unroll
    for (int mt = 0; mt < 2; ++mt)
        #pragma unroll
        for (int nt = 0; nt < 6; ++nt)
            yacc[mt][nt] = (f32x4){0.f, 0.f, 0.f, 0.f};

    const int arow = lane & 15;
    const int kgrp = (lane >> 4) * 8;
    const int drow = (lane >> 4) * 4;
    const int m0 = wv * 32;

    for (int hc = 0; hc < 6; ++hc) {
        __syncthreads();
        if (usews) {
            const bf16x8* s1 = (const bf16x8*)(wsb + WS_FC1 + hc * 6144);
            for (int v = tid; v < 768; v += 256) {
                int r = v / 12, c8 = (v - r * 12) * 8;
                *(bf16x8*)&W1S[r][c8] = s1[v];
            }
            const __hip_bfloat16* s2 = wsb + WS_FC2 + hc * 64;
            for (int v = tid; v < 768; v += 256) {
                int r = v >> 3, c8 = (v & 7) * 8;
                *(bf16x8*)&W2S[r][c8] = *(const bf16x8*)(s2 + r * 384 + c8);
            }
        } else {
            #pragma unroll
            for (int k = 0; k < 24; ++k) {
                int idx = tid + k * 256;
                int r = idx / 96, c = idx - r * 96;
                W1S[r][c] = __float2bfloat16(w1[hc * 6144 + idx]);
            }
            #pragma unroll
            for (int k = 0; k < 24; ++k) {
                int idx = tid + k * 256;
                int r = idx >> 6, c = idx & 63;
                W2S[r][c] = __float2bfloat16(w2[r * 384 + hc * 64 + c]);
            }
        }
        __syncthreads();

        f32x4 hacc[2][4];
        #pragma unroll
        for (int mt = 0; mt < 2; ++mt)
            #pragma unroll
            for (int nt = 0; nt < 4; ++nt)
                hacc[mt][nt] = (f32x4){0.f, 0.f, 0.f, 0.f};
        #pragma unroll
        for (int k = 0; k < 3; ++k) {
            bf16x8 a0 = *(const bf16x8*)&XS[m0 + arow][k * 32 + kgrp];
            bf16x8 a1 = *(const bf16x8*)&XS[m0 + 16 + arow][k * 32 + kgrp];
            #pragma unroll
            for (int nt = 0; nt < 4; ++nt) {
                bf16x8 b = *(const bf16x8*)&W1S[nt * 16 + arow][k * 32 + kgrp];
                hacc[0][nt] = __builtin_amdgcn_mfma_f32_16x16x32_bf16(a0, b, hacc[0][nt], 0, 0, 0);
                hacc[1][nt] = __builtin_amdgcn_mfma_f32_16x16x32_bf16(a1, b, hacc[1][nt], 0, 0, 0);
            }
        }
        #pragma unroll
        for (int mt = 0; mt < 2; ++mt)
            #pragma unroll
            for (int nt = 0; nt < 4; ++nt)
                #pragma unroll
                for (int r = 0; r < 4; ++r) {
                    float v = hacc[mt][nt][r] + b1[hc * 64 + nt * 16 + arow];
                    float g = 0.5f * v * (1.f + erff(v * 0.70710678118654752f));
                    HS[m0 + mt * 16 + drow + r][nt * 16 + arow] = __float2bfloat16(g);
                }
        #pragma unroll
        for (int k = 0; k < 2; ++k) {
            bf16x8 a0 = *(const bf16x8*)&HS[m0 + arow][k * 32 + kgrp];
            bf16x8 a1 = *(const bf16x8*)&HS[m0 + 16 + arow][k * 32 + kgrp];
            #pragma unroll
            for (int nt = 0; nt < 6; ++nt) {
                bf16x8 b = *(const bf16x8*)&W2S[nt * 16 + arow][k * 32 + kgrp];
                yacc[0][nt] = __builtin_amdgcn_mfma_f32_16x16x32_bf16(a0, b, yacc[0][nt], 0, 0, 0);
                yacc[1][nt] = __builtin_amdgcn_mfma_f32_16x16x32_bf16(a1, b, yacc[1][nt], 0, 0, 0);
            }
        }
    }

    #pragma unroll
    for (int mt = 0; mt < 2; ++mt)
        #pragma unroll
        for (int nt = 0; nt < 6; ++nt)
            #pragma unroll
            for (int r = 0; r < 4; ++r) {
                int t = tok0 + m0 + mt * 16 + drow + r;
                int c = nt * 16 + arow;
                int idx = t * 96 + c;
                io[idx] = io[idx] + yacc[mt][nt][r] + b2[c];
            }
}

extern "C" void kernel_launch(void* const* d_in, const int* in_sizes, int n_in,
                              void* d_out, int out_size, void* d_ws, size_t ws_size,
                              hipStream_t stream) {
    const float* x      = (const float*)d_in[0];
    const float* n1w    = (const float*)d_in[1];
    const float* n1b    = (const float*)d_in[2];
    const float* qkv_w  = (const float*)d_in[3];
    const float* qkv_b  = (const float*)d_in[4];
    const float* proj_w = (const float*)d_in[5];
    const float* proj_b = (const float*)d_in[6];
    const float* rpb    = (const float*)d_in[7];
    const float* n2w    = (const float*)d_in[8];
    const float* n2b    = (const float*)d_in[9];
    const float* fc1_w  = (const float*)d_in[10];
    const float* fc1_b  = (const float*)d_in[11];
    const float* fc2_w  = (const float*)d_in[12];
    const float* fc2_b  = (const float*)d_in[13];
    float* out = (float*)d_out;

    const int usews = (ws_size >= (size_t)WS_NEED) ? 1 : 0;
    __hip_bfloat16* wsb = (__hip_bfloat16*)d_ws;
    float* biasM = (float*)((char*)d_ws + WS_BIASM_BYTE);

    if (usews)
        prep_kernel<<<(WS_BF16_N + 37632 + 255) / 256, 256, 0, stream>>>(
            qkv_w, proj_w, fc1_w, fc2_w, rpb, wsb, biasM);

    attn_kernel<<<2048, 512, 0, stream>>>(x, n1w, n1b, qkv_w, qkv_b,
                                          proj_w, proj_b, rpb,
                                          wsb, biasM, usews, out);
    mlp_kernel<<<1568, 256, 0, stream>>>(n2w, n2b, fc1_w, fc1_b, fc2_w, fc2_b,
                                         wsb, usews, out);
}

// Round 5
// 474.580 us; speedup vs baseline: 22.0717x; 1.0431x over previous
//
#include <hip/hip_runtime.h>
#include <hip/hip_bf16.h>
#include <math.h>

// Swin Transformer 3D block, MI355X (gfx950).  R5.
// prep_kernel: bf16 weights into d_ws (Q-scale folded) + rel-pos bias in
//   SWAPPED score C-fragment layout (rows=u, cols=t).
// attn_kernel: per-window. LDS only for XS (LN'd x / attn-out), Kb, and a
//   region shared by Q-bounce then V^T (73 KB -> 2 blocks/CU). Weights are
//   read as MFMA B-fragments DIRECTLY from global bf16 (L2-hot). Scores are
//   computed swapped: P C-frag [u][t]; softmax is register-local (no max
//   subtraction: |scores| << 1 by construction); P->PV A-frag via 4-lane
//   __shfl redistribution. 5 barriers/block total.
// mlp_kernel: barrier-free chunk loop (B-frags from global, HS wave-private).

#define NTOK 98
#define SCALE 0.17677669529663687f

#define WS_PROJ   27648
#define WS_FC1    36864
#define WS_FC2    73728
#define WS_BF16_N 110592
#define WS_BIASM_BYTE 221184
#define WS_NEED   371712

typedef __attribute__((ext_vector_type(8))) short bf16x8;
typedef __attribute__((ext_vector_type(4))) float f32x4;

__device__ __forceinline__ int row_of(int wid, int t) {
    int b = wid >> 8, rem = wid & 255;
    int d0 = rem >> 6, h0 = (rem >> 3) & 7, w0 = rem & 7;
    int td = t / 49, tr = t % 49, th = tr / 7, tw = tr % 7;
    int dd = d0 * 2 + td, hh = h0 * 7 + th, ww = w0 * 7 + tw;
    return ((b * 8 + dd) * 56 + hh) * 56 + ww;
}

__device__ __forceinline__ int pcode(int t) {
    int a = t / 49, r = t - 49 * a, b = r / 7, c = r - 7 * b;
    return a * 169 + b * 13 + c;
}

__device__ __forceinline__ unsigned short f2bfu(float f) {
    __hip_bfloat16 h = __float2bfloat16(f);
    unsigned short u; __builtin_memcpy(&u, &h, 2); return u;
}
__device__ __forceinline__ unsigned int pk2(float lo, float hi) {
    return (unsigned int)f2bfu(lo) | ((unsigned int)f2bfu(hi) << 16);
}
__device__ __forceinline__ bf16x8 loadB(const __hip_bfloat16* wb, const float* wf,
                                        int usews, int idx) {
    if (usews) return *(const bf16x8*)(wb + idx);
    bf16x8 r;
    #pragma unroll
    for (int j = 0; j < 8; ++j) r[j] = (short)f2bfu(wf[idx + j]);
    return r;
}

// ---------------------------------------------------------------- prep
__global__ __launch_bounds__(256) void prep_kernel(
    const float* __restrict__ qkv_w, const float* __restrict__ proj_w,
    const float* __restrict__ fc1_w, const float* __restrict__ fc2_w,
    const float* __restrict__ rpb,
    __hip_bfloat16* __restrict__ wsb, float* __restrict__ biasM)
{
    int i = blockIdx.x * 256 + threadIdx.x;
    if (i < WS_BF16_N) {
        float v;
        if (i < 27648)      { v = qkv_w[i]; if (i < 9216) v *= SCALE; }
        else if (i < 36864) v = proj_w[i - 27648];
        else if (i < 73728) v = fc1_w[i - 36864];
        else                v = fc2_w[i - 73728];
        wsb[i] = __float2bfloat16(v);
    } else if (i < WS_BF16_N + 37632) {
        int j = i - WS_BF16_N;
        int r = j & 3, lane = (j >> 2) & 63;
        int rest = j >> 8;
        int U = rest % 7; rest /= 7;
        int Tt = rest % 7, h = rest / 7;
        int t = Tt * 16 + (lane & 15);              if (t > 97) t = 97;
        int u = U * 16 + ((lane >> 4) << 2) + r;    if (u > 97) u = 97;
        biasM[j] = rpb[(pcode(t) - pcode(u) + 253) * 3 + h];
    }
}

// ---------------------------------------------------------------- attention
__global__ __launch_bounds__(512, 4) void attn_kernel(
    const float* __restrict__ x,
    const float* __restrict__ n1w, const float* __restrict__ n1b,
    const float* __restrict__ qkv_w, const float* __restrict__ qkv_b,
    const float* __restrict__ proj_w, const float* __restrict__ proj_b,
    const float* __restrict__ rpb,
    const __hip_bfloat16* __restrict__ wsb, const float* __restrict__ biasM,
    int usews,
    float* __restrict__ out)
{
    __shared__ __align__(16) __hip_bfloat16 XS[112][104];  // LN'd x; later attn-out
    __shared__ __align__(16) __hip_bfloat16 Kb[112][104];
    __shared__ __align__(16) __hip_bfloat16 VQ[13056];     // QB[112][104] then vT[96][136]
    __shared__ int rowbase[NTOK];

    const int wid = blockIdx.x, tid = threadIdx.x;
    const int lane = tid & 63, wv = tid >> 6;
    const int l15 = lane & 15;
    const int g = lane >> 4;
    const int koff = g * 8;
    const int drow = g * 4;

    for (int t = tid; t < NTOK; t += 512) rowbase[t] = row_of(wid, t) * 96;
    // zero XS tail rows 98..111 (keeps pad-row GEMM outputs finite)
    for (int i = tid; i < 14 * 104; i += 512) {
        int r = 98 + i / 104, c = i % 104;
        XS[r][c] = __float2bfloat16(0.f);
    }

    // ---- LN1 -> XS bf16 (one wave per token)
    {
        float w0 = n1w[lane], b0 = n1b[lane];
        float w1 = (lane < 32) ? n1w[64 + lane] : 0.f;
        float b1 = (lane < 32) ? n1b[64 + lane] : 0.f;
        for (int t = wv; t < NTOK; t += 8) {
            int base = row_of(wid, t) * 96;
            float v0 = x[base + lane];
            float v1 = (lane < 32) ? x[base + 64 + lane] : 0.f;
            float s = v0 + v1;
            #pragma unroll
            for (int m = 32; m; m >>= 1) s += __shfl_xor(s, m, 64);
            float mean = s * (1.f / 96.f);
            float e0 = v0 - mean;
            float e1 = (lane < 32) ? (v1 - mean) : 0.f;
            float ss = e0 * e0 + e1 * e1;
            #pragma unroll
            for (int m = 32; m; m >>= 1) ss += __shfl_xor(ss, m, 64);
            float rstd = rsqrtf(ss * (1.f / 96.f) + 1e-5f);
            XS[t][lane] = __float2bfloat16(e0 * rstd * w0 + b0);
            if (lane < 32)
                XS[t][64 + lane] = __float2bfloat16(e1 * rstd * w1 + b1);
        }
    }
    __syncthreads();                                   // bar0: XS ready

    // ---- chunk q: Q = XS @ Wq^T (B-frags from global), C-frags -> QB bounce
    __hip_bfloat16* QB = &VQ[0];                       // [112][104]
    for (int tile = wv; tile < 42; tile += 8) {
        int m0 = (tile / 6) * 16, n0 = (tile % 6) * 16;
        f32x4 acc = {0.f, 0.f, 0.f, 0.f};
        #pragma unroll
        for (int ks = 0; ks < 3; ++ks) {
            bf16x8 a = *(const bf16x8*)&XS[m0 + l15][ks * 32 + koff];
            bf16x8 b = loadB(wsb, qkv_w, usews, (n0 + l15) * 96 + ks * 32 + koff);
            acc = __builtin_amdgcn_mfma_f32_16x16x32_bf16(a, b, acc, 0, 0, 0);
        }
        float bb = qkv_b[n0 + l15];
        #pragma unroll
        for (int r = 0; r < 4; ++r) {
            float q = usews ? (acc[r] + bb * SCALE) : ((acc[r] + bb) * SCALE);
            QB[(m0 + drow + r) * 104 + n0 + l15] = __float2bfloat16(q);
        }
    }
    __syncthreads();                                   // bar1: QB ready

    // ---- Q preload to registers (tasks: wave w owns tasks w, w+8, w+16)
    bf16x8 qf[3];
    #pragma unroll
    for (int i = 0; i < 3; ++i) {
        int task = wv + 8 * i;
        if (task < 21) {
            int s_ = task / 3, h_ = task - 3 * s_;
            qf[i] = *(const bf16x8*)&QB[(s_ * 16 + l15) * 104 + h_ * 32 + koff];
        }
    }
    __syncthreads();                                   // bar2: QB dead -> vT region

    // ---- vT tail zero (u 98..135) + chunks k, v
    __hip_bfloat16* vT = &VQ[0];                       // [96][136]
    for (int i = tid; i < 96 * 38; i += 512) {
        int r = i / 38, c = 98 + (i - r * 38);
        vT[r * 136 + c] = __float2bfloat16(0.f);
    }
    for (int c = 1; c < 3; ++c) {
        for (int tile = wv; tile < 42; tile += 8) {
            int m0 = (tile / 6) * 16, n0 = (tile % 6) * 16;
            f32x4 acc = {0.f, 0.f, 0.f, 0.f};
            #pragma unroll
            for (int ks = 0; ks < 3; ++ks) {
                bf16x8 a = *(const bf16x8*)&XS[m0 + l15][ks * 32 + koff];
                bf16x8 b = loadB(wsb + c * 9216, qkv_w + c * 9216, usews,
                                 (n0 + l15) * 96 + ks * 32 + koff);
                acc = __builtin_amdgcn_mfma_f32_16x16x32_bf16(a, b, acc, 0, 0, 0);
            }
            float bb = qkv_b[c * 96 + n0 + l15];
            if (c == 1) {
                #pragma unroll
                for (int r = 0; r < 4; ++r)
                    Kb[m0 + drow + r][n0 + l15] = __float2bfloat16(acc[r] + bb);
            } else {
                unsigned int d0 = pk2(acc[0] + bb, acc[1] + bb);
                unsigned int d1 = pk2(acc[2] + bb, acc[3] + bb);
                int u0 = m0 + drow;
                if (u0 < NTOK) {   // u0 multiple of 4; rows 96+ handled by zeros/mask
                    unsigned int* p = (unsigned int*)&vT[(n0 + l15) * 136 + u0];
                    p[0] = d0;
                    if (u0 + 2 < NTOK) p[1] = d1;
                }
            }
        }
    }
    __syncthreads();                                   // bar3: Kb, vT ready

    // ---- head loop, barrier-free: task = (strip, head)
    const bool oddg = (g >> 1) & 1;
    const int srcA = l15 + ((g & 1) << 5);
    const int srcB = srcA + 16;
    #pragma unroll 1
    for (int i = 0; i < 3; ++i) {
        int task = wv + 8 * i;
        if (task >= 21) break;
        int strip = task / 3, h = task - 3 * strip;

        // scores swapped: P[u][t] ; rows u = drow+r, cols t = l15
        f32x4 s[7];
        #pragma unroll
        for (int U = 0; U < 7; ++U) {
            bf16x8 ak = *(const bf16x8*)&Kb[U * 16 + l15][h * 32 + koff];
            f32x4 z = {0.f, 0.f, 0.f, 0.f};
            s[U] = __builtin_amdgcn_mfma_f32_16x16x32_bf16(ak, qf[i], z, 0, 0, 0);
        }
        // bias
        if (usews) {
            const float* bmb = biasM + (((h * 7 + strip) * 7) << 8) + (lane << 2);
            #pragma unroll
            for (int U = 0; U < 7; ++U) {
                f32x4 bv = *(const f32x4*)(bmb + (U << 8));
                s[U][0] += bv[0]; s[U][1] += bv[1]; s[U][2] += bv[2]; s[U][3] += bv[3];
            }
        } else {
            int tq = strip * 16 + l15; if (tq > 97) tq = 97;
            int pt = pcode(tq);
            #pragma unroll
            for (int U = 0; U < 7; ++U)
                #pragma unroll
                for (int r = 0; r < 4; ++r) {
                    int u = U * 16 + drow + r; if (u > 97) u = 97;
                    s[U][r] += rpb[(pt - pcode(u) + 253) * 3 + h];
                }
        }
        // mask u>=98 (tile 6)
        if (drow > 0) { s[6][0] = -1e30f; s[6][1] = -1e30f; }
        s[6][2] = -1e30f; s[6][3] = -1e30f;
        // exp (no max subtraction; scores bounded small) + column sum
        f32x4 sumv = {0.f, 0.f, 0.f, 0.f};
        #pragma unroll
        for (int U = 0; U < 7; ++U) {
            #pragma unroll
            for (int r = 0; r < 4; ++r) { s[U][r] = __expf(s[U][r]); sumv[r] += s[U][r]; }
        }
        float hs = sumv[0] + sumv[1] + sumv[2] + sumv[3];
        hs += __shfl_xor(hs, 16, 64);
        hs += __shfl_xor(hs, 32, 64);
        float inv = 1.f / hs;
        // normalize + pack to bf16 dwords
        unsigned int dwl[7], dwh[7];
        #pragma unroll
        for (int U = 0; U < 7; ++U) {
            dwl[U] = pk2(s[U][0] * inv, s[U][1] * inv);
            dwh[U] = pk2(s[U][2] * inv, s[U][3] * inv);
        }
        // PV: redistribute P into A-frags (4-lane shuffle), B = vT
        f32x4 acc0 = {0.f, 0.f, 0.f, 0.f}, acc1 = {0.f, 0.f, 0.f, 0.f};
        #pragma unroll
        for (int ks = 0; ks < 4; ++ks) {
            unsigned int D0, D1, D2, D3;
            if (ks < 3) {
                unsigned int e0 = __shfl((int)dwl[2 * ks], srcA, 64);
                unsigned int o0 = __shfl((int)dwl[2 * ks + 1], srcA, 64);
                unsigned int e1 = __shfl((int)dwh[2 * ks], srcA, 64);
                unsigned int o1 = __shfl((int)dwh[2 * ks + 1], srcA, 64);
                unsigned int e2 = __shfl((int)dwl[2 * ks], srcB, 64);
                unsigned int o2 = __shfl((int)dwl[2 * ks + 1], srcB, 64);
                unsigned int e3 = __shfl((int)dwh[2 * ks], srcB, 64);
                unsigned int o3 = __shfl((int)dwh[2 * ks + 1], srcB, 64);
                D0 = oddg ? o0 : e0; D1 = oddg ? o1 : e1;
                D2 = oddg ? o2 : e2; D3 = oddg ? o3 : e3;
            } else {
                unsigned int t0 = __shfl((int)dwl[6], srcA, 64);
                unsigned int t1 = __shfl((int)dwh[6], srcA, 64);
                unsigned int t2 = __shfl((int)dwl[6], srcB, 64);
                unsigned int t3 = __shfl((int)dwh[6], srcB, 64);
                D0 = (g < 2) ? t0 : 0u; D1 = (g < 2) ? t1 : 0u;
                D2 = (g < 2) ? t2 : 0u; D3 = (g < 2) ? t3 : 0u;
            }
            union { unsigned int d[4]; bf16x8 v; } af;
            af.d[0] = D0; af.d[1] = D1; af.d[2] = D2; af.d[3] = D3;
            bf16x8 b0 = *(const bf16x8*)&vT[(h * 32 + l15) * 136 + ks * 32 + koff];
            bf16x8 b1 = *(const bf16x8*)&vT[(h * 32 + 16 + l15) * 136 + ks * 32 + koff];
            acc0 = __builtin_amdgcn_mfma_f32_16x16x32_bf16(af.v, b0, acc0, 0, 0, 0);
            acc1 = __builtin_amdgcn_mfma_f32_16x16x32_bf16(af.v, b1, acc1, 0, 0, 0);
        }
        #pragma unroll
        for (int r = 0; r < 4; ++r) {
            XS[strip * 16 + drow + r][h * 32 + l15]      = __float2bfloat16(acc0[r]);
            XS[strip * 16 + drow + r][h * 32 + 16 + l15] = __float2bfloat16(acc1[r]);
        }
    }
    __syncthreads();                                   // bar4: attn-out ready

    // ---- proj GEMM + residual (B-frags from global)
    for (int tile = wv; tile < 42; tile += 8) {
        int m0 = (tile / 6) * 16, n0 = (tile % 6) * 16;
        f32x4 acc = {0.f, 0.f, 0.f, 0.f};
        #pragma unroll
        for (int ks = 0; ks < 3; ++ks) {
            bf16x8 a = *(const bf16x8*)&XS[m0 + l15][ks * 32 + koff];
            bf16x8 b = loadB(wsb + WS_PROJ, proj_w, usews,
                             (n0 + l15) * 96 + ks * 32 + koff);
            acc = __builtin_amdgcn_mfma_f32_16x16x32_bf16(a, b, acc, 0, 0, 0);
        }
        float pb = proj_b[n0 + l15];
        #pragma unroll
        for (int r = 0; r < 4; ++r) {
            int t = m0 + drow + r;
            if (t < NTOK) {
                int idx = rowbase[t] + n0 + l15;
                out[idx] = x[idx] + acc[r] + pb;
            }
        }
    }
}

// ---------------------------------------------------------------- MLP (MFMA)
__global__ __launch_bounds__(256, 3) void mlp_kernel(
    const float* __restrict__ n2w, const float* __restrict__ n2b,
    const float* __restrict__ w1, const float* __restrict__ b1,
    const float* __restrict__ w2, const float* __restrict__ b2,
    const __hip_bfloat16* __restrict__ wsb, int usews,
    float* __restrict__ io)
{
    __shared__ __align__(16) __hip_bfloat16 XS[128][104];
    __shared__ __align__(16) __hip_bfloat16 HS[128][72];

    const int tid = threadIdx.x, lane = tid & 63, wv = tid >> 6;
    const int tok0 = blockIdx.x * 128;
    const int arow = lane & 15;
    const int kgrp = (lane >> 4) * 8;
    const int drow = (lane >> 4) * 4;
    const int m0 = wv * 32;

    for (int t = wv; t < 128; t += 4) {
        int base = (tok0 + t) * 96;
        float v0 = io[base + lane];
        float v1 = (lane < 32) ? io[base + 64 + lane] : 0.f;
        float s = v0 + v1;
        #pragma unroll
        for (int m = 32; m; m >>= 1) s += __shfl_xor(s, m, 64);
        float mean = s * (1.f / 96.f);
        float e0 = v0 - mean;
        float e1 = (lane < 32) ? (v1 - mean) : 0.f;
        float ss = e0 * e0 + e1 * e1;
        #pragma unroll
        for (int m = 32; m; m >>= 1) ss += __shfl_xor(ss, m, 64);
        float rstd = rsqrtf(ss * (1.f / 96.f) + 1e-5f);
        XS[t][lane] = __float2bfloat16(e0 * rstd * n2w[lane] + n2b[lane]);
        if (lane < 32)
            XS[t][64 + lane] = __float2bfloat16(e1 * rstd * n2w[64 + lane] + n2b[64 + lane]);
    }
    __syncthreads();                                   // only barrier

    f32x4 yacc[2][6];
    #pragma unroll
    for (int mt = 0; mt < 2; ++mt)
        #pragma unroll
        for (int nt = 0; nt < 6; ++nt)
            yacc[mt][nt] = (f32x4){0.f, 0.f, 0.f, 0.f};

    for (int hc = 0; hc < 6; ++hc) {
        // GEMM1: H(32x64) = XS(32x96) @ W1[hc]^T  (B-frags from global)
        f32x4 hacc[2][4];
        #pragma unroll
        for (int mt = 0; mt < 2; ++mt)
            #pragma unroll
            for (int nt = 0; nt < 4; ++nt)
                hacc[mt][nt] = (f32x4){0.f, 0.f, 0.f, 0.f};
        #pragma unroll
        for (int k = 0; k < 3; ++k) {
            bf16x8 a0 = *(const bf16x8*)&XS[m0 + arow][k * 32 + kgrp];
            bf16x8 a1 = *(const bf16x8*)&XS[m0 + 16 + arow][k * 32 + kgrp];
            #pragma unroll
            for (int nt = 0; nt < 4; ++nt) {
                bf16x8 b = loadB(wsb + WS_FC1, w1, usews,
                                 (hc * 64 + nt * 16 + arow) * 96 + k * 32 + kgrp);
                hacc[0][nt] = __builtin_amdgcn_mfma_f32_16x16x32_bf16(a0, b, hacc[0][nt], 0, 0, 0);
                hacc[1][nt] = __builtin_amdgcn_mfma_f32_16x16x32_bf16(a1, b, hacc[1][nt], 0, 0, 0);
            }
        }
        #pragma unroll
        for (int mt = 0; mt < 2; ++mt)
            #pragma unroll
            for (int nt = 0; nt < 4; ++nt)
                #pragma unroll
                for (int r = 0; r < 4; ++r) {
                    float v = hacc[mt][nt][r] + b1[hc * 64 + nt * 16 + arow];
                    float gl = 0.5f * v * (1.f + erff(v * 0.70710678118654752f));
                    HS[m0 + mt * 16 + drow + r][nt * 16 + arow] = __float2bfloat16(gl);
                }
        // GEMM2 partial: Y += GELU(H) @ W2[:,hc]^T  (HS wave-private, no barrier)
        #pragma unroll
        for (int k = 0; k < 2; ++k) {
            bf16x8 a0 = *(const bf16x8*)&HS[m0 + arow][k * 32 + kgrp];
            bf16x8 a1 = *(const bf16x8*)&HS[m0 + 16 + arow][k * 32 + kgrp];
            #pragma unroll
            for (int nt = 0; nt < 6; ++nt) {
                bf16x8 b = loadB(wsb + WS_FC2, w2, usews,
                                 (nt * 16 + arow) * 384 + hc * 64 + k * 32 + kgrp);
                yacc[0][nt] = __builtin_amdgcn_mfma_f32_16x16x32_bf16(a0, b, yacc[0][nt], 0, 0, 0);
                yacc[1][nt] = __builtin_amdgcn_mfma_f32_16x16x32_bf16(a1, b, yacc[1][nt], 0, 0, 0);
            }
        }
    }

    #pragma unroll
    for (int mt = 0; mt < 2; ++mt)
        #pragma unroll
        for (int nt = 0; nt < 6; ++nt)
            #pragma unroll
            for (int r = 0; r < 4; ++r) {
                int t = tok0 + m0 + mt * 16 + drow + r;
                int c = nt * 16 + arow;
                int idx = t * 96 + c;
                io[idx] = io[idx] + yacc[mt][nt][r] + b2[c];
            }
}

extern "C" void kernel_launch(void* const* d_in, const int* in_sizes, int n_in,
                              void* d_out, int out_size, void* d_ws, size_t ws_size,
                              hipStream_t stream) {
    const float* x      = (const float*)d_in[0];
    const float* n1w    = (const float*)d_in[1];
    const float* n1b    = (const float*)d_in[2];
    const float* qkv_w  = (const float*)d_in[3];
    const float* qkv_b  = (const float*)d_in[4];
    const float* proj_w = (const float*)d_in[5];
    const float* proj_b = (const float*)d_in[6];
    const float* rpb    = (const float*)d_in[7];
    const float* n2w    = (const float*)d_in[8];
    const float* n2b    = (const float*)d_in[9];
    const float* fc1_w  = (const float*)d_in[10];
    const float* fc1_b  = (const float*)d_in[11];
    const float* fc2_w  = (const float*)d_in[12];
    const float* fc2_b  = (const float*)d_in[13];
    float* out = (float*)d_out;

    const int usews = (ws_size >= (size_t)WS_NEED) ? 1 : 0;
    __hip_bfloat16* wsb = (__hip_bfloat16*)d_ws;
    float* biasM = (float*)((char*)d_ws + WS_BIASM_BYTE);

    if (usews)
        prep_kernel<<<(WS_BF16_N + 37632 + 255) / 256, 256, 0, stream>>>(
            qkv_w, proj_w, fc1_w, fc2_w, rpb, wsb, biasM);

    attn_kernel<<<2048, 512, 0, stream>>>(x, n1w, n1b, qkv_w, qkv_b,
                                          proj_w, proj_b, rpb,
                                          wsb, biasM, usews, out);
    mlp_kernel<<<1568, 256, 0, stream>>>(n2w, n2b, fc1_w, fc1_b, fc2_w, fc2_b,
                                         wsb, usews, out);
}